// Round 2
// baseline (336.692 us; speedup 1.0000x reference)
//
#include <hip/hip_runtime.h>

#define B_TOTAL 16384
#define F 39
#define E 64
#define U 128
#define BT 64           // b-rows per block
#define THREADS 256

typedef __attribute__((ext_vector_type(8))) short short8;   // 8 bf16 (4 VGPRs)
typedef __attribute__((ext_vector_type(4))) float f32x4;    // MFMA accumulator

// pack two f32 -> two bf16 (round-half-up on the dropped 16 bits; bias negligible)
__device__ __forceinline__ unsigned pack2_bf16(float a, float b) {
  unsigned ua = __builtin_bit_cast(unsigned, a) + 0x8000u;
  unsigned ub = __builtin_bit_cast(unsigned, b) + 0x8000u;
  return (ub & 0xFFFF0000u) | (ua >> 16);
}

__global__ __launch_bounds__(THREADS) void fused_outer(
    const float* __restrict__ embeds, const float* __restrict__ w,
    float* __restrict__ out) {
  // Ft: feat_sum tile, f32, row stride 68 floats (272 B, 16B-aligned, bank-shift 4/row)
  __shared__ __align__(16) float Ft[BT * 68];
  // Gs: G chunk (64 b x 64 j) bf16, row stride 72 shorts (144 B -> balanced frag reads)
  __shared__ __align__(16) short Gs[BT * 72];
  // Ws: W chunk (128 u x 64 j) bf16, row stride 72 shorts
  __shared__ __align__(16) short Ws[U * 72];

  const int t = threadIdx.x;
  const int b0 = blockIdx.x * BT;

  // ---------------- Phase 1: feat_sum over F into Ft ----------------
  // 1024 (b, e4) tasks; thread handles 4. Lanes 0..15 cover one row's 64 floats
  // -> coalesced 256B segments per 16 lanes.
  #pragma unroll
  for (int task = t; task < BT * 16; task += THREADS) {
    int b = task >> 4, e4 = task & 15;
    const float4* src = (const float4*)(embeds + (size_t)(b0 + b) * (F * E)) + e4;
    float4 s = make_float4(0.f, 0.f, 0.f, 0.f);
    #pragma unroll
    for (int f = 0; f < F; ++f) {
      float4 v = src[f * (E / 4)];
      s.x += v.x; s.y += v.y; s.z += v.z; s.w += v.w;
    }
    *(float4*)&Ft[b * 68 + e4 * 4] = s;
  }
  __syncthreads();

  // G-generation ownership: thread owns row grow, 16 columns at gq*16, kept in regs
  const int grow = t >> 2, gq = t & 3;
  float fr[16];
  #pragma unroll
  for (int j = 0; j < 16; ++j) fr[j] = Ft[grow * 68 + gq * 16 + j];

  // Wave/fragment indexing: waves 2x2 over the 64x128 output tile
  const int lane = t & 63, wave = t >> 6;
  const int mh = (wave >> 1) * 32;   // wave's row offset (2 m-tiles)
  const int nh = (wave & 1) * 64;    // wave's col offset (4 n-tiles)
  const int fl = lane & 15;          // fragment row/col index
  const int fo = (lane >> 4) * 8;    // fragment k-octet offset

  // W staging ownership: thread stages 32 floats of row wu
  const int wu = t >> 1;
  const int wjh = (t & 1) * 32;

  f32x4 acc[2][4];
  #pragma unroll
  for (int mt = 0; mt < 2; ++mt)
    #pragma unroll
    for (int nt = 0; nt < 4; ++nt)
      #pragma unroll
      for (int r = 0; r < 4; ++r) acc[mt][nt][r] = 0.f;

  // ---------------- K-loop: 64 chunks (one i each, BK = 64) ----------------
  for (int i = 0; i < E; ++i) {
    __syncthreads();   // previous chunk's MFMA reads done before overwrite

    // G chunk: Gs[b][j] = bf16(Ft[b][i] * Ft[b][j])
    {
      float fi = Ft[grow * 68 + i];
      unsigned gp[8];
      #pragma unroll
      for (int p = 0; p < 8; ++p)
        gp[p] = pack2_bf16(fi * fr[2 * p], fi * fr[2 * p + 1]);
      uint4* dst = (uint4*)&Gs[grow * 72 + gq * 16];
      dst[0] = make_uint4(gp[0], gp[1], gp[2], gp[3]);
      dst[1] = make_uint4(gp[4], gp[5], gp[6], gp[7]);
    }
    // W chunk: Ws[u][j] = bf16(w[u, i, j]) for all 128 u
    {
      const float4* wsrc = (const float4*)(w + (size_t)wu * (E * E) + i * E + wjh);
      unsigned wp[16];
      #pragma unroll
      for (int p = 0; p < 8; ++p) {
        float4 v = wsrc[p];
        wp[2 * p]     = pack2_bf16(v.x, v.y);
        wp[2 * p + 1] = pack2_bf16(v.z, v.w);
      }
      uint4* dst = (uint4*)&Ws[wu * 72 + wjh];
      #pragma unroll
      for (int p = 0; p < 4; ++p)
        dst[p] = make_uint4(wp[4 * p], wp[4 * p + 1], wp[4 * p + 2], wp[4 * p + 3]);
    }
    __syncthreads();

    // MFMA: 2 k-steps of 32; C[b,u] += G[b,k] * W[u,k]  (B^T fragment reads)
    #pragma unroll
    for (int ks = 0; ks < 2; ++ks) {
      short8 a[2], bb[4];
      #pragma unroll
      for (int mt = 0; mt < 2; ++mt)
        a[mt] = *(const short8*)&Gs[(mh + mt * 16 + fl) * 72 + ks * 32 + fo];
      #pragma unroll
      for (int nt = 0; nt < 4; ++nt)
        bb[nt] = *(const short8*)&Ws[(nh + nt * 16 + fl) * 72 + ks * 32 + fo];
      #pragma unroll
      for (int mt = 0; mt < 2; ++mt)
        #pragma unroll
        for (int nt = 0; nt < 4; ++nt)
          acc[mt][nt] = __builtin_amdgcn_mfma_f32_16x16x32_bf16(
              a[mt], bb[nt], acc[mt][nt], 0, 0, 0);
    }
  }

  // ---------------- Epilogue: C/D layout col=lane&15 (u), row=(lane>>4)*4+r (b) ----
  const int r0 = (lane >> 4) * 4;
  #pragma unroll
  for (int mt = 0; mt < 2; ++mt) {
    #pragma unroll
    for (int nt = 0; nt < 4; ++nt) {
      #pragma unroll
      for (int r = 0; r < 4; ++r) {
        int row = b0 + mh + mt * 16 + r0 + r;
        int col = nh + nt * 16 + fl;
        out[(size_t)row * U + col] = acc[mt][nt][r];
      }
    }
  }
}

extern "C" void kernel_launch(void* const* d_in, const int* in_sizes, int n_in,
                              void* d_out, int out_size, void* d_ws, size_t ws_size,
                              hipStream_t stream) {
  const float* embeds = (const float*)d_in[0];
  const float* w      = (const float*)d_in[1];
  float* out          = (float*)d_out;
  fused_outer<<<dim3(B_TOTAL / BT), dim3(THREADS), 0, stream>>>(embeds, w, out);
}

// Round 3
// 250.685 us; speedup vs baseline: 1.3431x; 1.3431x over previous
//
#include <hip/hip_runtime.h>

#define B_TOTAL 16384
#define F 39
#define E 64
#define U 128
#define BT 64            // b-rows per block
#define THREADS 512      // 8 waves

typedef __attribute__((ext_vector_type(8))) short short8;   // 8 bf16
typedef __attribute__((ext_vector_type(4))) float f32x4;

// pack two f32 -> packed bf16 pair (round-half-up)
__device__ __forceinline__ unsigned pack2_bf16(float a, float b) {
  unsigned ua = __builtin_bit_cast(unsigned, a) + 0x8000u;
  unsigned ub = __builtin_bit_cast(unsigned, b) + 0x8000u;
  return (ub & 0xFFFF0000u) | (ua >> 16);
}

// ---- prep: W (U,E,E) f32 -> fragment-ordered bf16 in ws (1 MB) ----
// wf[(i*8+ntg)*2+ks][lane] (16 B) = bf16(W[ntg*16+(lane&15)][i][ks*32+(lane>>4)*8 .. +7])
__global__ __launch_bounds__(256) void prep_w(const float* __restrict__ w,
                                              uint4* __restrict__ wf) {
  int tid = blockIdx.x * 256 + threadIdx.x;   // 65536 = 1024 frags * 64 lanes
  int lane = tid & 63;
  int frag = tid >> 6;
  int ks  = frag & 1;
  int ntg = (frag >> 1) & 7;
  int i   = frag >> 4;
  int uu  = ntg * 16 + (lane & 15);
  int k0  = ks * 32 + (lane >> 4) * 8;
  const float* src = w + (size_t)uu * (E * E) + i * E + k0;
  float4 v0 = *(const float4*)src;
  float4 v1 = *(const float4*)(src + 4);
  uint4 o;
  o.x = pack2_bf16(v0.x, v0.y);
  o.y = pack2_bf16(v0.z, v0.w);
  o.z = pack2_bf16(v1.x, v1.y);
  o.w = pack2_bf16(v1.z, v1.w);
  wf[tid] = o;
}

__global__ __launch_bounds__(THREADS) void fused_outer(
    const float* __restrict__ embeds, const uint4* __restrict__ wf,
    float* __restrict__ out) {
  __shared__ __align__(16) float Ft[BT * 68];   // [b][e], pad stride 68
  __shared__ __align__(16) float FtT[E * 68];   // [e][b], pad stride 68

  const int t = threadIdx.x;
  const int b0 = blockIdx.x * BT;

  // ---------------- Phase 1: feat_sum over F ----------------
  for (int task = t; task < BT * 16; task += THREADS) {
    int b = task >> 4, e4 = task & 15;
    const float4* src = (const float4*)(embeds + (size_t)(b0 + b) * (F * E)) + e4;
    float4 s = make_float4(0.f, 0.f, 0.f, 0.f);
    #pragma unroll
    for (int f = 0; f < F; ++f) {
      float4 v = src[f * (E / 4)];
      s.x += v.x; s.y += v.y; s.z += v.z; s.w += v.w;
    }
    *(float4*)&Ft[b * 68 + e4 * 4] = s;
    FtT[(e4 * 4 + 0) * 68 + b] = s.x;
    FtT[(e4 * 4 + 1) * 68 + b] = s.y;
    FtT[(e4 * 4 + 2) * 68 + b] = s.z;
    FtT[(e4 * 4 + 3) * 68 + b] = s.w;
  }
  __syncthreads();   // the ONLY barrier

  const int lane = t & 63;
  const int wave = t >> 6;           // 0..7 -> 2m x 4n grid of 32x32 wave tiles
  const int mh   = (wave >> 2) * 32;
  const int ncol = wave & 3;
  const int nh   = ncol * 32;
  const int fl   = lane & 15;
  const int fo   = (lane >> 4) * 8;
  const int r0   = (lane >> 4) * 4;

  // A-fragments, i-independent: af[mt][ks] = bf16(f[mh+mt*16+fl][ks*32+fo .. +7])
  short8 af[2][2];
  #pragma unroll
  for (int mt = 0; mt < 2; ++mt) {
    const float* fr = &Ft[(mh + mt * 16 + fl) * 68];
    #pragma unroll
    for (int ks = 0; ks < 2; ++ks) {
      float4 v0 = *(const float4*)&fr[ks * 32 + fo];
      float4 v1 = *(const float4*)&fr[ks * 32 + fo + 4];
      uint4 o;
      o.x = pack2_bf16(v0.x, v0.y);
      o.y = pack2_bf16(v0.z, v0.w);
      o.z = pack2_bf16(v1.x, v1.y);
      o.w = pack2_bf16(v1.z, v1.w);
      af[mt][ks] = __builtin_bit_cast(short8, o);
    }
  }

  f32x4 acc[2][2];
  #pragma unroll
  for (int mt = 0; mt < 2; ++mt)
    #pragma unroll
    for (int nt = 0; nt < 2; ++nt)
      #pragma unroll
      for (int r = 0; r < 4; ++r) acc[mt][nt][r] = 0.f;

  const uint4* wbase = wf + lane;
  const int fragq = ncol * 4;   // frag = i*16 + ncol*4 + (nt*2+ks)

  #define LOADW(buf, ii) {                                        \
    _Pragma("unroll")                                             \
    for (int q = 0; q < 4; ++q)                                   \
      buf[q] = wbase[(size_t)(((ii) * 16 + fragq + q)) * 64]; }

  #define STEP(ii, buf) {                                                     \
    f32x4 fia = *(const f32x4*)&FtT[(ii) * 68 + mh + r0];                     \
    f32x4 fib = *(const f32x4*)&FtT[(ii) * 68 + mh + 16 + r0];                \
    _Pragma("unroll")                                                         \
    for (int nt = 0; nt < 2; ++nt) {                                          \
      f32x4 s0 = {0.f, 0.f, 0.f, 0.f};                                        \
      s0 = __builtin_amdgcn_mfma_f32_16x16x32_bf16(                           \
          af[0][0], __builtin_bit_cast(short8, buf[nt * 2 + 0]), s0, 0, 0, 0);\
      s0 = __builtin_amdgcn_mfma_f32_16x16x32_bf16(                           \
          af[0][1], __builtin_bit_cast(short8, buf[nt * 2 + 1]), s0, 0, 0, 0);\
      acc[0][nt] += fia * s0;                                                 \
      f32x4 s1 = {0.f, 0.f, 0.f, 0.f};                                        \
      s1 = __builtin_amdgcn_mfma_f32_16x16x32_bf16(                           \
          af[1][0], __builtin_bit_cast(short8, buf[nt * 2 + 0]), s1, 0, 0, 0);\
      s1 = __builtin_amdgcn_mfma_f32_16x16x32_bf16(                           \
          af[1][1], __builtin_bit_cast(short8, buf[nt * 2 + 1]), s1, 0, 0, 0);\
      acc[1][nt] += fib * s1;                                                 \
    } }

  // K-loop over i: no barriers, W fragments register-double-buffered depth 2
  uint4 w0[4], w1[4], w2[4], w3[4];
  LOADW(w0, 0);
  LOADW(w1, 1);
  for (int i = 0; i < E; i += 4) {
    LOADW(w2, i + 2);
    STEP(i, w0);
    LOADW(w3, i + 3);
    STEP(i + 1, w1);
    if (i + 4 < E) LOADW(w0, i + 4);
    STEP(i + 2, w2);
    if (i + 5 < E) LOADW(w1, i + 5);
    STEP(i + 3, w3);
  }

  // Epilogue: C/D layout col=lane&15 (u), row=(lane>>4)*4+r (b)
  #pragma unroll
  for (int mt = 0; mt < 2; ++mt)
    #pragma unroll
    for (int nt = 0; nt < 2; ++nt)
      #pragma unroll
      for (int r = 0; r < 4; ++r)
        out[(size_t)(b0 + mh + mt * 16 + r0 + r) * U + (nh + nt * 16 + fl)] =
            acc[mt][nt][r];
}

extern "C" void kernel_launch(void* const* d_in, const int* in_sizes, int n_in,
                              void* d_out, int out_size, void* d_ws, size_t ws_size,
                              hipStream_t stream) {
  const float* embeds = (const float*)d_in[0];
  const float* w      = (const float*)d_in[1];
  float* out          = (float*)d_out;
  uint4* wfrag        = (uint4*)d_ws;   // needs 1 MiB scratch
  prep_w<<<dim3(256), dim3(256), 0, stream>>>(w, wfrag);
  fused_outer<<<dim3(B_TOTAL / BT), dim3(THREADS), 0, stream>>>(embeds, wfrag, out);
}